// Round 1
// baseline (283.884 us; speedup 1.0000x reference)
//
#include <hip/hip_runtime.h>
#include <hip/hip_bf16.h>

#define NB 32
#define NS 1024
#define ND 768
#define BS_TOT (NB * NS)  // 32768

// sim scale = 1 / (0.7 * sqrt(768))
#define SCALE 0.05154913f

// ---------------------------------------------------------------------------
// Linearized SupCon: exp(sim/N) = 1 + sim/N + O(1e-6 rel). The loss collapses
// to per-batch group sums g_P, batch sum G, per-anchor dots f_i.(G-g_P) and
// |f_i|^2, plus label-only counts. O(B*S*D), two feature passes, no Gram.
//
// Round-10 restructure (occupancy/latency):
//  - gsum: row-parallel via LDS float atomics (ds_add_f32), 8 waves/block,
//    float4 loads. Old design was 1 wave/SIMD with per-thread serial row loop.
//  - anchor: dG read from global (1.6 MB, L2-resident) instead of a 48 KB LDS
//    stage; grid 1024 -> 4 blocks/CU; creduce + group folded in.
//  - int64-vs-int32 labels resolved host-side from in_sizes[1]; labI removed.
// ---------------------------------------------------------------------------

// ---------------- Kernel 1: per-anchor metadata (labels only) --------------
// nlater via parallel histogram scan:
//   rank_i = #same-label before i;  nlat_i = gs - 1 - rank_i
//   thread t owns anchors 4t..4t+3; hist[t][L] = own count, 8-step
//   Hillis-Steele inclusive scan over rows -> hist[t][L] = sum_{k<=t}.
__global__ __launch_bounds__(256) void meta_kernel(
    const int* __restrict__ lr, int i64, float* __restrict__ invN,
    float* __restrict__ invGS, float* __restrict__ numneg,
    float* __restrict__ nlat, float* __restrict__ cntG,
    float* __restrict__ gnorm, float* __restrict__ out) {
  __shared__ int labs[NS];        // 4 KB
  __shared__ int hist[256][17];   // 17 KB (pad 17 -> conflict-free columns)
  __shared__ int cnt[16];
  int b = blockIdx.x, t = threadIdx.x;
  if (t < 16) cnt[t] = 0;
  __syncthreads();
  for (int i = t; i < NS; i += 256) {
    int gi = b * NS + i;
    int lab = (i64 ? lr[2 * gi] : lr[gi]) & 15;
    labs[i] = lab;
    atomicAdd(&cnt[lab], 1);
  }
#pragma unroll
  for (int L = 0; L < 16; ++L) hist[t][L] = 0;
  __syncthreads();
  // Own labels (4 contiguous anchors per thread) + own histogram row.
  int lab4[4];
#pragma unroll
  for (int e = 0; e < 4; ++e) {
    lab4[e] = labs[t * 4 + e];
    hist[t][lab4[e]]++;
  }
  __syncthreads();
  // Inclusive Hillis-Steele scan over the 256 rows, 16 bins wide.
#pragma unroll
  for (int off = 1; off < 256; off <<= 1) {
    int tmp[16];
#pragma unroll
    for (int L = 0; L < 16; ++L) tmp[L] = (t >= off) ? hist[t - off][L] : 0;
    __syncthreads();
#pragma unroll
    for (int L = 0; L < 16; ++L) hist[t][L] += tmp[L];
    __syncthreads();
  }
  // Emit per-anchor metadata.
#pragma unroll
  for (int e = 0; e < 4; ++e) {
    int i = t * 4 + e;
    int gi = b * NS + i;
    int lab = lab4[e];
    int gs = cnt[lab];
    int nn = NS - gs;
    int later_own = 0;
#pragma unroll
    for (int e2 = 0; e2 < 4; ++e2)
      if (e2 > e && lab4[e2] == lab) later_own++;
    int rank = hist[t][lab] - 1 - later_own;
    invN[gi] = nn > 0 ? 1.0f / (float)nn : 0.0f;
    invGS[gi] = 1.0f / (float)gs;
    numneg[gi] = (float)nn;
    nlat[gi] = (float)(gs - 1 - rank);
  }
  if (t < 16) {
    cntG[b * 16 + t] = (float)cnt[t];
    gnorm[b * 16 + t] = 0.0f;  // ws is poisoned; zero before greduce atomics
  }
  if (b == 0 && t == 0) out[0] = 0.0f;
}

// ---------------- Kernel 2: partial group sums -----------------------------
// Grid 256 = 32 batches x 8 row-chunks(128), 512 threads = 8 waves. Waves
// process rows in parallel; accumulation into acc[16][768] via LDS float
// atomics (ds_add_f32, fire-and-forget -> no dependent RMW chains). Loads are
// float4 (16 B/lane). The stride-4 ds_add pattern is ~8-way bank-conflicted
// but the total LDS-pipe time (~4 us/block) hides under the ~15 us HBM time.
__global__ __launch_bounds__(512) void gsum_kernel(
    const float* __restrict__ feat, const int* __restrict__ lr, int i64,
    float* __restrict__ gsumP) {
  const int b = blockIdx.x >> 3, rc = blockIdx.x & 7;
  __shared__ float acc[16 * ND];  // 48 KB
  __shared__ int labs[128];
  const int t = threadIdx.x;
  {
    float4* az = (float4*)acc;
    for (int i = t; i < 16 * ND / 4; i += 512)
      az[i] = make_float4(0.f, 0.f, 0.f, 0.f);
  }
  if (t < 128) {
    int gi = b * NS + rc * 128 + t;
    labs[t] = (i64 ? lr[2 * gi] : lr[gi]) & 15;
  }
  __syncthreads();
  const int w = t >> 6, l = t & 63;
  const float* fp = feat + (size_t)(b * NS + rc * 128) * ND;
  for (int r = w; r < 128; r += 8) {
    const float* row = fp + (size_t)r * ND;
    float4 v[3];
#pragma unroll
    for (int c = 0; c < 3; ++c)
      v[c] = *(const float4*)(row + 4 * l + 256 * c);
    float* arow = acc + labs[r] * ND;
#pragma unroll
    for (int c = 0; c < 3; ++c) {
      float* p = arow + 4 * l + 256 * c;
      atomicAdd(p + 0, v[c].x);
      atomicAdd(p + 1, v[c].y);
      atomicAdd(p + 2, v[c].z);
      atomicAdd(p + 3, v[c].w);
    }
  }
  __syncthreads();
  {
    float4* o = (float4*)(gsumP + (size_t)blockIdx.x * 16 * ND);
    const float4* a4 = (const float4*)acc;
    for (int i = t; i < 16 * ND / 4; i += 512) o[i] = a4[i];
  }
}

// ---------------- Kernel 3: reduce partials, build dG = G - g_P, ||g_P||^2 -
// 192 blocks (32 batches x 6 dim-chunks of 128) x 128 threads.
__global__ __launch_bounds__(128) void greduce_kernel(
    const float* __restrict__ gsumP, float* __restrict__ dG,
    float* __restrict__ gnorm) {
  const int b = blockIdx.x / 6, ck = blockIdx.x % 6;
  const int d = ck * 128 + threadIdx.x;
  float g[16];
#pragma unroll
  for (int gi = 0; gi < 16; ++gi) g[gi] = 0.0f;
  for (int rc = 0; rc < 8; ++rc) {
    const float* p = gsumP + (size_t)(b * 8 + rc) * 16 * ND + d;
#pragma unroll
    for (int gi = 0; gi < 16; ++gi) g[gi] += p[gi * ND];
  }
  float G = 0.0f;
#pragma unroll
  for (int gi = 0; gi < 16; ++gi) G += g[gi];
#pragma unroll
  for (int gi = 0; gi < 16; ++gi)
    dG[(size_t)(b * 16 + gi) * ND + d] = G - g[gi];
#pragma unroll
  for (int gi = 0; gi < 16; ++gi) {
    float v = g[gi] * g[gi];
#pragma unroll
    for (int m = 1; m < 64; m <<= 1) v += __shfl_xor(v, m);
    if ((threadIdx.x & 63) == 0) atomicAdd(&gnorm[b * 16 + gi], v);
  }
}

// ---------------- Kernel 4: per-anchor dots -> loss (fused reduce) ---------
// No LDS stage: dG is 1.6 MB total -> L2-resident (16x reuse per batch at
// ~34.5 TB/s aggregate). Grid 1024 = 32 batches x 32 chunks of 32 anchors,
// 256 threads, no LDS cap -> 4 blocks/CU. Each wave: 8 rows, 2 in flight.
// Per-block reduction + one atomic replaces the old creduce kernel; block 0
// also folds in the per-group -||g_P||^2 terms (old group_kernel).
__global__ __launch_bounds__(256) void anchor_kernel(
    const float* __restrict__ feat, const int* __restrict__ lr, int i64,
    const float* __restrict__ dG, const float* __restrict__ invN,
    const float* __restrict__ invGS, const float* __restrict__ numneg,
    const float* __restrict__ nlat, const float* __restrict__ gnorm,
    const float* __restrict__ cntG, float* __restrict__ out) {
  const int b = blockIdx.x >> 5, rc = blockIdx.x & 31;
  const int t = threadIdx.x, w = t >> 6, l = t & 63;
  __shared__ float ws[4];
  float vsum = 0.0f;
  for (int r0 = 0; r0 < 8; r0 += 2) {
    const int a0 = b * NS + rc * 32 + w * 8 + r0;
    const int a1 = a0 + 1;
    const int lab0 = (i64 ? lr[2 * a0] : lr[a0]) & 15;
    const int lab1 = (i64 ? lr[2 * a1] : lr[a1]) & 15;
    const float* f0 = feat + (size_t)a0 * ND;
    const float* f1 = feat + (size_t)a1 * ND;
    const float* g0 = dG + (size_t)(b * 16 + lab0) * ND;
    const float* g1 = dG + (size_t)(b * 16 + lab1) * ND;
    float d10 = 0.0f, sq0 = 0.0f, d11 = 0.0f, sq1 = 0.0f;
#pragma unroll
    for (int c = 0; c < 3; ++c) {
      float4 fa = *(const float4*)(f0 + l * 4 + 256 * c);
      float4 fb = *(const float4*)(f1 + l * 4 + 256 * c);
      float4 ga = *(const float4*)(g0 + l * 4 + 256 * c);
      float4 gb = *(const float4*)(g1 + l * 4 + 256 * c);
      d10 += fa.x * ga.x + fa.y * ga.y + fa.z * ga.z + fa.w * ga.w;
      sq0 += fa.x * fa.x + fa.y * fa.y + fa.z * fa.z + fa.w * fa.w;
      d11 += fb.x * gb.x + fb.y * gb.y + fb.z * gb.z + fb.w * gb.w;
      sq1 += fb.x * fb.x + fb.y * fb.y + fb.z * fb.z + fb.w * fb.w;
    }
#pragma unroll
    for (int m = 1; m < 64; m <<= 1) {
      d10 += __shfl_xor(d10, m);
      sq0 += __shfl_xor(sq0, m);
      d11 += __shfl_xor(d11, m);
      sq1 += __shfl_xor(sq1, m);
    }
    if (l < 2) {
      int a = (l == 0) ? a0 : a1;
      float d1 = (l == 0) ? d10 : d11;
      float sq = (l == 0) ? sq0 : sq1;
      float N = numneg[a];
      if (N > 0.0f) {
        float neg = N + d1 * SCALE * invN[a];  // linearized neg_logits
        vsum += (nlat[a] * __logf(neg) + 0.5f * SCALE * sq) * invGS[a];
      }
    }
  }
  // Block-level reduction of the per-anchor contributions (lanes 0/1 hold
  // one anchor's value per iteration; everyone else is 0).
  float s2 = vsum + __shfl_xor(vsum, 1);
  if (l == 0) ws[w] = s2;
  __syncthreads();
  if (t == 0)
    atomicAdd(out, (ws[0] + ws[1] + ws[2] + ws[3]) * (1.0f / NS));
  // Block 0 additionally folds in the per-group -0.5*SCALE*||g_P||^2/|P|
  // terms (gnorm completed by greduce; stream order guarantees visibility).
  if (blockIdx.x == 0) {
    float gv = 0.0f;
#pragma unroll
    for (int k = 0; k < 2; ++k) {
      int idx = t + k * 256;  // 512 = 32 batches x 16 groups
      float c = cntG[idx];
      if (c > 0.0f && c < (float)NS)
        gv += -0.5f * SCALE * gnorm[idx] / c;
    }
#pragma unroll
    for (int m = 1; m < 64; m <<= 1) gv += __shfl_xor(gv, m);
    __syncthreads();  // ws reuse: thread 0 finished reading above
    if (l == 0) ws[w] = gv;
    __syncthreads();
    if (t == 0)
      atomicAdd(out, (ws[0] + ws[1] + ws[2] + ws[3]) * (1.0f / NS));
  }
}

extern "C" void kernel_launch(void* const* d_in, const int* in_sizes, int n_in,
                              void* d_out, int out_size, void* d_ws,
                              size_t ws_size, hipStream_t stream) {
  (void)out_size;
  (void)ws_size;
  const float* feat = (const float*)d_in[0];
  const int* labels = (const int*)d_in[1];
  float* out = (float*)d_out;
  // Labels dtype resolved host-side from the input byte size (int64 from the
  // jax reference = 8 B/elem). Defaults to int64 when ambiguous.
  const int i64 = (n_in > 1 && in_sizes[1] == BS_TOT * 4) ? 0 : 1;

  char* w = (char*)d_ws;
  float* gsumP = (float*)w;  // [32][8][16][768] = 12.6 MB
  size_t off = (size_t)NB * 8 * 16 * ND * 4;
  float* dG = (float*)(w + off);  // [32][16][768] = 1.6 MB
  off += (size_t)NB * 16 * ND * 4;
  float* invN = (float*)(w + off);
  off += (size_t)BS_TOT * 4;
  float* invGS = (float*)(w + off);
  off += (size_t)BS_TOT * 4;
  float* numneg = (float*)(w + off);
  off += (size_t)BS_TOT * 4;
  float* nlat = (float*)(w + off);
  off += (size_t)BS_TOT * 4;
  float* cntG = (float*)(w + off);
  off += (size_t)NB * 16 * 4;
  float* gnorm = (float*)(w + off);
  off += (size_t)NB * 16 * 4;
  // total ws usage ~14.8 MB

  meta_kernel<<<NB, 256, 0, stream>>>(labels, i64, invN, invGS, numneg, nlat,
                                      cntG, gnorm, out);
  gsum_kernel<<<NB * 8, 512, 0, stream>>>(feat, labels, i64, gsumP);
  greduce_kernel<<<NB * 6, 128, 0, stream>>>(gsumP, dG, gnorm);
  anchor_kernel<<<NB * 32, 256, 0, stream>>>(feat, labels, i64, dG, invN,
                                             invGS, numneg, nlat, gnorm, cntG,
                                             out);
}

// Round 2
// 203.634 us; speedup vs baseline: 1.3941x; 1.3941x over previous
//
#include <hip/hip_runtime.h>
#include <hip/hip_bf16.h>

#define NB 32
#define NS 1024
#define ND 768
#define BS_TOT (NB * NS)  // 32768

// sim scale = 1 / (0.7 * sqrt(768))
#define SCALE 0.05154913f

// ---------------------------------------------------------------------------
// Linearized SupCon: exp(sim/N) = 1 + sim/N + O(1e-6 rel). The loss collapses
// to per-batch group sums g_P, batch sum G, per-anchor dots f_i.(G-g_P) and
// |f_i|^2, plus label-only counts. O(B*S*D), two feature passes, no Gram.
//
// Round-11: gsum rewritten with pure-register accumulators.
//  - Round-10's LDS float atomics serialized on same-address RMW chains
//    (131 us, VALUBusy 0.4%). Root cause: aliasing atomics run at latency,
//    not throughput.
//  - New scheme: thread t owns dims {t,t+256,t+512}; waves own disjoint dims
//    -> acc[16][3] lives in 48 VGPRs. Row label is wave-uniform -> hoisted
//    to SGPR (readfirstlane) + switch -> scalar branches, no runtime VGPR
//    indexing (no scratch), no LDS, no atomics. 8-row load batches keep 24
//    coalesced loads in flight. Grid 512 (64 rows/block) -> 2 blocks/CU.
// ---------------------------------------------------------------------------

// ---------------- Kernel 1: per-anchor metadata (labels only) --------------
__global__ __launch_bounds__(256) void meta_kernel(
    const int* __restrict__ lr, int i64, float* __restrict__ invN,
    float* __restrict__ invGS, float* __restrict__ numneg,
    float* __restrict__ nlat, float* __restrict__ cntG,
    float* __restrict__ gnorm, float* __restrict__ out) {
  __shared__ int labs[NS];        // 4 KB
  __shared__ int hist[256][17];   // 17 KB (pad 17 -> conflict-free columns)
  __shared__ int cnt[16];
  int b = blockIdx.x, t = threadIdx.x;
  if (t < 16) cnt[t] = 0;
  __syncthreads();
  for (int i = t; i < NS; i += 256) {
    int gi = b * NS + i;
    int lab = (i64 ? lr[2 * gi] : lr[gi]) & 15;
    labs[i] = lab;
    atomicAdd(&cnt[lab], 1);
  }
#pragma unroll
  for (int L = 0; L < 16; ++L) hist[t][L] = 0;
  __syncthreads();
  // Own labels (4 contiguous anchors per thread) + own histogram row.
  int lab4[4];
#pragma unroll
  for (int e = 0; e < 4; ++e) {
    lab4[e] = labs[t * 4 + e];
    hist[t][lab4[e]]++;
  }
  __syncthreads();
  // Inclusive Hillis-Steele scan over the 256 rows, 16 bins wide.
#pragma unroll
  for (int off = 1; off < 256; off <<= 1) {
    int tmp[16];
#pragma unroll
    for (int L = 0; L < 16; ++L) tmp[L] = (t >= off) ? hist[t - off][L] : 0;
    __syncthreads();
#pragma unroll
    for (int L = 0; L < 16; ++L) hist[t][L] += tmp[L];
    __syncthreads();
  }
  // Emit per-anchor metadata.
#pragma unroll
  for (int e = 0; e < 4; ++e) {
    int i = t * 4 + e;
    int gi = b * NS + i;
    int lab = lab4[e];
    int gs = cnt[lab];
    int nn = NS - gs;
    int later_own = 0;
#pragma unroll
    for (int e2 = 0; e2 < 4; ++e2)
      if (e2 > e && lab4[e2] == lab) later_own++;
    int rank = hist[t][lab] - 1 - later_own;
    invN[gi] = nn > 0 ? 1.0f / (float)nn : 0.0f;
    invGS[gi] = 1.0f / (float)gs;
    numneg[gi] = (float)nn;
    nlat[gi] = (float)(gs - 1 - rank);
  }
  if (t < 16) {
    cntG[b * 16 + t] = (float)cnt[t];
    gnorm[b * 16 + t] = 0.0f;  // ws is poisoned; zero before greduce atomics
  }
  if (b == 0 && t == 0) out[0] = 0.0f;
}

// ---------------- Kernel 2: partial group sums (register accumulators) -----
// Grid 512 = 32 batches x 16 row-chunks(64), 256 threads. Thread t owns dims
// {t, t+256, t+512}: acc[16][3] in VGPRs. Row label is wave-uniform ->
// readfirstlane + switch = scalar branch, 3 v_add_f32 per row. No LDS acc,
// no atomics. 8-row batches keep 24 coalesced loads in flight.
#define GSUM_CASE(G)                   \
  case G:                              \
    acc[G][0] += v[u][0];              \
    acc[G][1] += v[u][1];              \
    acc[G][2] += v[u][2];              \
    break;

__global__ __launch_bounds__(256) void gsum_kernel(
    const float* __restrict__ feat, const int* __restrict__ lr, int i64,
    float* __restrict__ gsumP) {
  const int b = blockIdx.x >> 4, rc = blockIdx.x & 15;
  __shared__ int labs[64];
  const int t = threadIdx.x;
  if (t < 64) {
    int gi = b * NS + rc * 64 + t;
    labs[t] = (i64 ? lr[2 * gi] : lr[gi]) & 15;
  }
  __syncthreads();
  float acc[16][3];
#pragma unroll
  for (int g = 0; g < 16; ++g)
#pragma unroll
    for (int c = 0; c < 3; ++c) acc[g][c] = 0.0f;
  const float* fp = feat + (size_t)(b * NS + rc * 64) * ND;
  for (int r0 = 0; r0 < 64; r0 += 8) {
    float v[8][3];
#pragma unroll
    for (int u = 0; u < 8; ++u)
#pragma unroll
      for (int c = 0; c < 3; ++c)
        v[u][c] = fp[(size_t)(r0 + u) * ND + t + 256 * c];
#pragma unroll
    for (int u = 0; u < 8; ++u) {
      const int lab = __builtin_amdgcn_readfirstlane(labs[r0 + u]);
      switch (lab) {
        GSUM_CASE(0) GSUM_CASE(1) GSUM_CASE(2) GSUM_CASE(3)
        GSUM_CASE(4) GSUM_CASE(5) GSUM_CASE(6) GSUM_CASE(7)
        GSUM_CASE(8) GSUM_CASE(9) GSUM_CASE(10) GSUM_CASE(11)
        GSUM_CASE(12) GSUM_CASE(13) GSUM_CASE(14) GSUM_CASE(15)
      }
    }
  }
  // Coalesced store of the block's partial [16][768] (consecutive t -> dims).
  float* o = gsumP + (size_t)blockIdx.x * 16 * ND;
#pragma unroll
  for (int g = 0; g < 16; ++g)
#pragma unroll
    for (int c = 0; c < 3; ++c) o[g * ND + t + 256 * c] = acc[g][c];
}

// ---------------- Kernel 3: reduce partials, build dG = G - g_P, ||g_P||^2 -
// 192 blocks (32 batches x 6 dim-chunks of 128) x 128 threads; 16 partials.
__global__ __launch_bounds__(128) void greduce_kernel(
    const float* __restrict__ gsumP, float* __restrict__ dG,
    float* __restrict__ gnorm) {
  const int b = blockIdx.x / 6, ck = blockIdx.x % 6;
  const int d = ck * 128 + threadIdx.x;
  float g[16];
#pragma unroll
  for (int gi = 0; gi < 16; ++gi) g[gi] = 0.0f;
  for (int rc = 0; rc < 16; ++rc) {
    const float* p = gsumP + (size_t)(b * 16 + rc) * 16 * ND + d;
#pragma unroll
    for (int gi = 0; gi < 16; ++gi) g[gi] += p[gi * ND];
  }
  float G = 0.0f;
#pragma unroll
  for (int gi = 0; gi < 16; ++gi) G += g[gi];
#pragma unroll
  for (int gi = 0; gi < 16; ++gi)
    dG[(size_t)(b * 16 + gi) * ND + d] = G - g[gi];
#pragma unroll
  for (int gi = 0; gi < 16; ++gi) {
    float v = g[gi] * g[gi];
#pragma unroll
    for (int m = 1; m < 64; m <<= 1) v += __shfl_xor(v, m);
    if ((threadIdx.x & 63) == 0) atomicAdd(&gnorm[b * 16 + gi], v);
  }
}

// ---------------- Kernel 4: per-anchor dots -> loss (fused reduce) ---------
// dG read from global (1.6 MB, L2-resident). Grid 1024 = 32 batches x 32
// chunks of 32 anchors, 256 threads, no LDS cap. Per-block reduction + one
// atomic; block 0 folds in the per-group -||g_P||^2 terms.
__global__ __launch_bounds__(256) void anchor_kernel(
    const float* __restrict__ feat, const int* __restrict__ lr, int i64,
    const float* __restrict__ dG, const float* __restrict__ invN,
    const float* __restrict__ invGS, const float* __restrict__ numneg,
    const float* __restrict__ nlat, const float* __restrict__ gnorm,
    const float* __restrict__ cntG, float* __restrict__ out) {
  const int b = blockIdx.x >> 5, rc = blockIdx.x & 31;
  const int t = threadIdx.x, w = t >> 6, l = t & 63;
  __shared__ float ws[4];
  float vsum = 0.0f;
  for (int r0 = 0; r0 < 8; r0 += 2) {
    const int a0 = b * NS + rc * 32 + w * 8 + r0;
    const int a1 = a0 + 1;
    const int lab0 = (i64 ? lr[2 * a0] : lr[a0]) & 15;
    const int lab1 = (i64 ? lr[2 * a1] : lr[a1]) & 15;
    const float* f0 = feat + (size_t)a0 * ND;
    const float* f1 = feat + (size_t)a1 * ND;
    const float* g0 = dG + (size_t)(b * 16 + lab0) * ND;
    const float* g1 = dG + (size_t)(b * 16 + lab1) * ND;
    float d10 = 0.0f, sq0 = 0.0f, d11 = 0.0f, sq1 = 0.0f;
#pragma unroll
    for (int c = 0; c < 3; ++c) {
      float4 fa = *(const float4*)(f0 + l * 4 + 256 * c);
      float4 fb = *(const float4*)(f1 + l * 4 + 256 * c);
      float4 ga = *(const float4*)(g0 + l * 4 + 256 * c);
      float4 gb = *(const float4*)(g1 + l * 4 + 256 * c);
      d10 += fa.x * ga.x + fa.y * ga.y + fa.z * ga.z + fa.w * ga.w;
      sq0 += fa.x * fa.x + fa.y * fa.y + fa.z * fa.z + fa.w * fa.w;
      d11 += fb.x * gb.x + fb.y * gb.y + fb.z * gb.z + fb.w * gb.w;
      sq1 += fb.x * fb.x + fb.y * fb.y + fb.z * fb.z + fb.w * fb.w;
    }
#pragma unroll
    for (int m = 1; m < 64; m <<= 1) {
      d10 += __shfl_xor(d10, m);
      sq0 += __shfl_xor(sq0, m);
      d11 += __shfl_xor(d11, m);
      sq1 += __shfl_xor(sq1, m);
    }
    if (l < 2) {
      int a = (l == 0) ? a0 : a1;
      float d1 = (l == 0) ? d10 : d11;
      float sq = (l == 0) ? sq0 : sq1;
      float N = numneg[a];
      if (N > 0.0f) {
        float neg = N + d1 * SCALE * invN[a];  // linearized neg_logits
        vsum += (nlat[a] * __logf(neg) + 0.5f * SCALE * sq) * invGS[a];
      }
    }
  }
  // Block-level reduction of the per-anchor contributions.
  float s2 = vsum + __shfl_xor(vsum, 1);
  if (l == 0) ws[w] = s2;
  __syncthreads();
  if (t == 0)
    atomicAdd(out, (ws[0] + ws[1] + ws[2] + ws[3]) * (1.0f / NS));
  // Block 0 additionally folds in the per-group -0.5*SCALE*||g_P||^2/|P|.
  if (blockIdx.x == 0) {
    float gv = 0.0f;
#pragma unroll
    for (int k = 0; k < 2; ++k) {
      int idx = t + k * 256;  // 512 = 32 batches x 16 groups
      float c = cntG[idx];
      if (c > 0.0f && c < (float)NS)
        gv += -0.5f * SCALE * gnorm[idx] / c;
    }
#pragma unroll
    for (int m = 1; m < 64; m <<= 1) gv += __shfl_xor(gv, m);
    __syncthreads();  // ws reuse: thread 0 finished reading above
    if (l == 0) ws[w] = gv;
    __syncthreads();
    if (t == 0)
      atomicAdd(out, (ws[0] + ws[1] + ws[2] + ws[3]) * (1.0f / NS));
  }
}

extern "C" void kernel_launch(void* const* d_in, const int* in_sizes, int n_in,
                              void* d_out, int out_size, void* d_ws,
                              size_t ws_size, hipStream_t stream) {
  (void)out_size;
  (void)ws_size;
  const float* feat = (const float*)d_in[0];
  const int* labels = (const int*)d_in[1];
  float* out = (float*)d_out;
  // Labels dtype resolved host-side from the input byte size.
  const int i64 = (n_in > 1 && in_sizes[1] == BS_TOT * 4) ? 0 : 1;

  char* w = (char*)d_ws;
  float* gsumP = (float*)w;  // [32][16][16][768] = 25.2 MB
  size_t off = (size_t)NB * 16 * 16 * ND * 4;
  float* dG = (float*)(w + off);  // [32][16][768] = 1.6 MB
  off += (size_t)NB * 16 * ND * 4;
  float* invN = (float*)(w + off);
  off += (size_t)BS_TOT * 4;
  float* invGS = (float*)(w + off);
  off += (size_t)BS_TOT * 4;
  float* numneg = (float*)(w + off);
  off += (size_t)BS_TOT * 4;
  float* nlat = (float*)(w + off);
  off += (size_t)BS_TOT * 4;
  float* cntG = (float*)(w + off);
  off += (size_t)NB * 16 * 4;
  float* gnorm = (float*)(w + off);
  off += (size_t)NB * 16 * 4;
  // total ws usage ~27.5 MB

  meta_kernel<<<NB, 256, 0, stream>>>(labels, i64, invN, invGS, numneg, nlat,
                                      cntG, gnorm, out);
  gsum_kernel<<<NB * 16, 256, 0, stream>>>(feat, labels, i64, gsumP);
  greduce_kernel<<<NB * 6, 128, 0, stream>>>(gsumP, dG, gnorm);
  anchor_kernel<<<NB * 32, 256, 0, stream>>>(feat, labels, i64, dG, invN,
                                             invGS, numneg, nlat, gnorm, cntG,
                                             out);
}

// Round 3
// 189.287 us; speedup vs baseline: 1.4998x; 1.0758x over previous
//
#include <hip/hip_runtime.h>
#include <hip/hip_bf16.h>

#define NB 32
#define NS 1024
#define ND 768
#define BS_TOT (NB * NS)  // 32768

// sim scale = 1 / (0.7 * sqrt(768))
#define SCALE 0.05154913f

// ---------------------------------------------------------------------------
// Linearized SupCon: exp(sim/N) = 1 + sim/N + O(1e-6 rel). The loss collapses
// to per-batch group sums g_P, batch sum G, per-anchor dots f_i.(G-g_P) and
// |f_i|^2, plus label-only counts. O(B*S*D), two feature passes, no Gram.
//
// Round-12: label-sorted gsum.
//  - Round-10 (LDS float atomics): 131 us — aliasing atomics serialize.
//  - Round-11 (VGPR acc + 16-case switch/row): ~48 us — per-row label
//    dispatch (branch chain / if-conversion) serializes rows, defeats load
//    batching. Lesson: NO per-row label logic of any kind.
//  - Round-12: meta already knows each anchor's within-group rank; a 16-entry
//    prefix gives a label-sorted permutation order[b][1024] for free. gsum
//    grid = (batch,label): each block streams its group's gathered rows —
//    pure float4 load+add, no switch, no atomics, no partials, single-writer
//    store to g[b][lab]. greduce's 25 MB partial traffic deleted; tiny gprep
//    builds dG/gnorm and folds the group term.
// ---------------------------------------------------------------------------

// ---------------- Kernel 1: per-anchor metadata (labels only) --------------
// Emits: meta4[a] = {invN, invGS, numneg, nlat}, order[b][1024] (label-sorted
// row permutation), startG/cntI[b][16].
__global__ __launch_bounds__(256) void meta_kernel(
    const int* __restrict__ lr, int i64, float4* __restrict__ meta4,
    int* __restrict__ order, int* __restrict__ startG, int* __restrict__ cntI,
    float* __restrict__ out) {
  __shared__ int labs[NS];        // 4 KB
  __shared__ int hist[256][17];   // 17 KB (pad 17 -> conflict-free columns)
  __shared__ int cnt[16];
  __shared__ int startL[16];
  int b = blockIdx.x, t = threadIdx.x;
  if (t < 16) cnt[t] = 0;
  __syncthreads();
  for (int i = t; i < NS; i += 256) {
    int gi = b * NS + i;
    int lab = (i64 ? lr[2 * gi] : lr[gi]) & 15;
    labs[i] = lab;
    atomicAdd(&cnt[lab], 1);
  }
#pragma unroll
  for (int L = 0; L < 16; ++L) hist[t][L] = 0;
  __syncthreads();
  // Own labels (4 contiguous anchors per thread) + own histogram row.
  int lab4[4];
#pragma unroll
  for (int e = 0; e < 4; ++e) {
    lab4[e] = labs[t * 4 + e];
    hist[t][lab4[e]]++;
  }
  __syncthreads();
  // Inclusive Hillis-Steele scan over the 256 rows, 16 bins wide.
#pragma unroll
  for (int off = 1; off < 256; off <<= 1) {
    int tmp[16];
#pragma unroll
    for (int L = 0; L < 16; ++L) tmp[L] = (t >= off) ? hist[t - off][L] : 0;
    __syncthreads();
#pragma unroll
    for (int L = 0; L < 16; ++L) hist[t][L] += tmp[L];
    __syncthreads();
  }
  // Exclusive prefix of group counts -> group start offsets.
  if (t == 0) {
    int s = 0;
#pragma unroll
    for (int L = 0; L < 16; ++L) {
      startL[L] = s;
      s += cnt[L];
    }
  }
  __syncthreads();
  // Emit per-anchor metadata + sorted-order scatter.
#pragma unroll
  for (int e = 0; e < 4; ++e) {
    int i = t * 4 + e;
    int gi = b * NS + i;
    int lab = lab4[e];
    int gs = cnt[lab];
    int nn = NS - gs;
    int later_own = 0;
#pragma unroll
    for (int e2 = 0; e2 < 4; ++e2)
      if (e2 > e && lab4[e2] == lab) later_own++;
    int rank = hist[t][lab] - 1 - later_own;
    float invN = nn > 0 ? 1.0f / (float)nn : 0.0f;
    meta4[gi] = make_float4(invN, 1.0f / (float)gs, (float)nn,
                            (float)(gs - 1 - rank));
    order[b * NS + startL[lab] + rank] = i;
  }
  if (t < 16) {
    startG[b * 16 + t] = startL[t];
    cntI[b * 16 + t] = cnt[t];
  }
  if (b == 0 && t == 0) out[0] = 0.0f;
}

// ---------------- Kernel 2: group sums over label-sorted rows --------------
// Grid 512 = 32 batches x 16 labels, 192 threads (3 waves). Thread t owns
// dims 4t..4t+3 (one float4 = whole 768-dim row per block). Pure streaming:
// batches of 16 gathered rows (16 dwordx4 in flight = 256 B/lane), no label
// logic, no atomics; single-writer float4 store to g[b][lab].
__global__ __launch_bounds__(192) void gsum_kernel(
    const float* __restrict__ feat, const int* __restrict__ order,
    const int* __restrict__ startG, const int* __restrict__ cntI,
    float* __restrict__ g) {
  const int b = blockIdx.x >> 4, lab = blockIdx.x & 15;
  const int start = startG[b * 16 + lab];
  const int n = cntI[b * 16 + lab];
  const int t = threadIdx.x;
  __shared__ int ord[NS];  // 4 KB; handles any group size
  for (int i = t; i < n; i += 192) ord[i] = order[b * NS + start + i];
  __syncthreads();
  const float* fb = feat + (size_t)b * NS * ND;
  float ax = 0.f, ay = 0.f, az = 0.f, aw = 0.f;
  const int full = n & ~15;
  for (int r = 0; r < full; r += 16) {
    float4 v[16];
#pragma unroll
    for (int u = 0; u < 16; ++u) {
      const int idx = __builtin_amdgcn_readfirstlane(ord[r + u]);
      v[u] = *(const float4*)(fb + (size_t)idx * ND + 4 * t);
    }
#pragma unroll
    for (int u = 0; u < 16; ++u) {
      ax += v[u].x;
      ay += v[u].y;
      az += v[u].z;
      aw += v[u].w;
    }
  }
  if (full < n) {  // masked tail batch: loads stay pipelined, adds masked
    const int rem = n - full;  // 1..15
    float4 v[16];
#pragma unroll
    for (int u = 0; u < 16; ++u) {
      int rr = full + (u < rem ? u : rem - 1);
      const int idx = __builtin_amdgcn_readfirstlane(ord[rr]);
      v[u] = *(const float4*)(fb + (size_t)idx * ND + 4 * t);
    }
#pragma unroll
    for (int u = 0; u < 16; ++u) {
      const float m = (u < rem) ? 1.0f : 0.0f;
      ax += m * v[u].x;
      ay += m * v[u].y;
      az += m * v[u].z;
      aw += m * v[u].w;
    }
  }
  float* o = g + ((size_t)(b * 16 + lab)) * ND + 4 * t;
  *(float4*)o = make_float4(ax, ay, az, aw);
}

// ---------------- Kernel 3: g -> dG = G - g_P, gnorm, group loss term ------
// 32 blocks x 192 threads. g is 1.5 MB, just written -> L2. Also folds the
// per-group -0.5*SCALE*||g_P||^2/|P| loss term (one atomic per block).
__global__ __launch_bounds__(192) void gprep_kernel(
    const float* __restrict__ g, const int* __restrict__ cntI,
    float* __restrict__ dG, float* __restrict__ out) {
  const int b = blockIdx.x, t = threadIdx.x;
  const int w = t >> 6, l = t & 63;
  const float* gb = g + (size_t)b * 16 * ND;
  float4 gv[16];
#pragma unroll
  for (int P = 0; P < 16; ++P)
    gv[P] = *(const float4*)(gb + P * ND + 4 * t);
  float4 G4 = make_float4(0.f, 0.f, 0.f, 0.f);
#pragma unroll
  for (int P = 0; P < 16; ++P) {
    G4.x += gv[P].x;
    G4.y += gv[P].y;
    G4.z += gv[P].z;
    G4.w += gv[P].w;
  }
  float* db = dG + (size_t)b * 16 * ND;
#pragma unroll
  for (int P = 0; P < 16; ++P)
    *(float4*)(db + P * ND + 4 * t) = make_float4(
        G4.x - gv[P].x, G4.y - gv[P].y, G4.z - gv[P].z, G4.w - gv[P].w);
  float nrm[16];
#pragma unroll
  for (int P = 0; P < 16; ++P)
    nrm[P] = gv[P].x * gv[P].x + gv[P].y * gv[P].y + gv[P].z * gv[P].z +
             gv[P].w * gv[P].w;
#pragma unroll
  for (int m = 1; m < 64; m <<= 1)
#pragma unroll
    for (int P = 0; P < 16; ++P) nrm[P] += __shfl_xor(nrm[P], m);
  __shared__ float red[3][16];
  if (l == 0)
#pragma unroll
    for (int P = 0; P < 16; ++P) red[w][P] = nrm[P];
  __syncthreads();
  if (t < 16) {
    float s = red[0][t] + red[1][t] + red[2][t];
    float c = (float)cntI[b * 16 + t];
    float val = (c > 0.5f && c < (float)NS - 0.5f) ? (-0.5f * SCALE * s / c)
                                                   : 0.0f;
#pragma unroll
    for (int m = 1; m < 16; m <<= 1) val += __shfl_xor(val, m);
    if (t == 0) atomicAdd(out, val * (1.0f / NS));
  }
}

// ---------------- Kernel 4: per-anchor dots -> loss (fused reduce) ---------
// dG read from global (1.6 MB, L2-resident). Grid 1024 = 32 batches x 32
// chunks of 32 anchors, 256 threads. meta4 = {invN, invGS, numneg, nlat}
// fused into one dwordx4 load. Per-block reduction + one atomic.
__global__ __launch_bounds__(256) void anchor_kernel(
    const float* __restrict__ feat, const int* __restrict__ lr, int i64,
    const float* __restrict__ dG, const float4* __restrict__ meta4,
    float* __restrict__ out) {
  const int b = blockIdx.x >> 5, rc = blockIdx.x & 31;
  const int t = threadIdx.x, w = t >> 6, l = t & 63;
  __shared__ float ws[4];
  float vsum = 0.0f;
  for (int r0 = 0; r0 < 8; r0 += 2) {
    const int a0 = b * NS + rc * 32 + w * 8 + r0;
    const int a1 = a0 + 1;
    const int lab0 = (i64 ? lr[2 * a0] : lr[a0]) & 15;
    const int lab1 = (i64 ? lr[2 * a1] : lr[a1]) & 15;
    const float* f0 = feat + (size_t)a0 * ND;
    const float* f1 = feat + (size_t)a1 * ND;
    const float* g0 = dG + (size_t)(b * 16 + lab0) * ND;
    const float* g1 = dG + (size_t)(b * 16 + lab1) * ND;
    float d10 = 0.0f, sq0 = 0.0f, d11 = 0.0f, sq1 = 0.0f;
#pragma unroll
    for (int c = 0; c < 3; ++c) {
      float4 fa = *(const float4*)(f0 + l * 4 + 256 * c);
      float4 fb = *(const float4*)(f1 + l * 4 + 256 * c);
      float4 ga = *(const float4*)(g0 + l * 4 + 256 * c);
      float4 gb = *(const float4*)(g1 + l * 4 + 256 * c);
      d10 += fa.x * ga.x + fa.y * ga.y + fa.z * ga.z + fa.w * ga.w;
      sq0 += fa.x * fa.x + fa.y * fa.y + fa.z * fa.z + fa.w * fa.w;
      d11 += fb.x * gb.x + fb.y * gb.y + fb.z * gb.z + fb.w * gb.w;
      sq1 += fb.x * fb.x + fb.y * fb.y + fb.z * fb.z + fb.w * fb.w;
    }
#pragma unroll
    for (int m = 1; m < 64; m <<= 1) {
      d10 += __shfl_xor(d10, m);
      sq0 += __shfl_xor(sq0, m);
      d11 += __shfl_xor(d11, m);
      sq1 += __shfl_xor(sq1, m);
    }
    if (l < 2) {
      int a = (l == 0) ? a0 : a1;
      float d1 = (l == 0) ? d10 : d11;
      float sq = (l == 0) ? sq0 : sq1;
      float4 md = meta4[a];  // {invN, invGS, numneg, nlat}
      if (md.z > 0.0f) {
        float neg = md.z + d1 * SCALE * md.x;  // linearized neg_logits
        vsum += (md.w * __logf(neg) + 0.5f * SCALE * sq) * md.y;
      }
    }
  }
  // Block-level reduction of the per-anchor contributions.
  float s2 = vsum + __shfl_xor(vsum, 1);
  if (l == 0) ws[w] = s2;
  __syncthreads();
  if (t == 0)
    atomicAdd(out, (ws[0] + ws[1] + ws[2] + ws[3]) * (1.0f / NS));
}

extern "C" void kernel_launch(void* const* d_in, const int* in_sizes, int n_in,
                              void* d_out, int out_size, void* d_ws,
                              size_t ws_size, hipStream_t stream) {
  (void)out_size;
  (void)ws_size;
  const float* feat = (const float*)d_in[0];
  const int* labels = (const int*)d_in[1];
  float* out = (float*)d_out;
  // Labels dtype resolved host-side from the input byte size.
  const int i64 = (n_in > 1 && in_sizes[1] == BS_TOT * 4) ? 0 : 1;

  char* w = (char*)d_ws;
  float4* meta4 = (float4*)w;  // [32768] float4 = 512 KB
  size_t off = (size_t)BS_TOT * 16;
  int* order = (int*)(w + off);  // [32][1024]
  off += (size_t)BS_TOT * 4;
  int* startG = (int*)(w + off);  // [32][16]
  off += (size_t)NB * 16 * 4;
  int* cntI = (int*)(w + off);  // [32][16]
  off += (size_t)NB * 16 * 4;
  float* g = (float*)(w + off);  // [32][16][768] = 1.5 MB
  off += (size_t)NB * 16 * ND * 4;
  float* dG = (float*)(w + off);  // [32][16][768] = 1.5 MB
  off += (size_t)NB * 16 * ND * 4;
  // total ws usage ~3.8 MB

  meta_kernel<<<NB, 256, 0, stream>>>(labels, i64, meta4, order, startG, cntI,
                                      out);
  gsum_kernel<<<NB * 16, 192, 0, stream>>>(feat, order, startG, cntI, g);
  gprep_kernel<<<NB, 192, 0, stream>>>(g, cntI, dG, out);
  anchor_kernel<<<NB * 32, 256, 0, stream>>>(feat, labels, i64, dG, meta4,
                                             out);
}

// Round 4
// 161.105 us; speedup vs baseline: 1.7621x; 1.1749x over previous
//
#include <hip/hip_runtime.h>
#include <hip/hip_bf16.h>

#define NB 32
#define NS 1024
#define ND 768
#define BS_TOT (NB * NS)  // 32768

// sim scale = 1 / (0.7 * sqrt(768))
#define SCALE 0.05154913f

// ---------------------------------------------------------------------------
// Fully-collapsed linearized SupCon (round 13). Two linearizations, both with
// error far below the f32 ULP of the ~1e2-magnitude loss:
//   exp(sim/N) = 1 + sim/N            (rel err ~1e-6, verified rounds 7-12)
//   log(N + SCALE*invN*d1) = log N + SCALE*d1/N^2   (d1*SCALE/N^2 ~ 5e-5,
//                                      2nd-order term ~2e-8 in the loss)
// With log linear in d1 = f_i.(G - g_P), every per-anchor term collapses to
// per-group sums computable in ONE streaming pass over features:
//   g_P   = sum_{i in P} f_i
//   h_P   = sum_{i in P} nlat_i * f_i      (nlat_i = gs-1-rank_i)
//   ssq_P = sum_{i in P} ||f_i||^2
//   loss  = (1/S) sum_{b,P: 0<|P|<S} (1/gs) * [ gs(gs-1)/2 * log N
//            + (SCALE/N^2) * h_P.(G - g_P) + 0.5*SCALE*(ssq_P - ||g_P||^2) ]
// The 96 MB second feature pass (anchor kernel) is deleted entirely.
// Structure: meta (labels only) -> gsum (one 96 MB pass) -> final (3 MB L2).
// ---------------------------------------------------------------------------

// ---------------- Kernel 1: label metadata -> packed sorted order ----------
// orderP[b][start_P + rank_i] = i | (nlat_i << 12); startG/cntI[b][16].
__global__ __launch_bounds__(256) void meta_kernel(
    const int* __restrict__ lr, int i64, int* __restrict__ orderP,
    int* __restrict__ startG, int* __restrict__ cntI,
    float* __restrict__ out) {
  __shared__ int labs[NS];        // 4 KB
  __shared__ int hist[256][17];   // 17 KB (pad 17 -> conflict-free columns)
  __shared__ int cnt[16];
  __shared__ int startL[16];
  int b = blockIdx.x, t = threadIdx.x;
  if (t < 16) cnt[t] = 0;
  __syncthreads();
  for (int i = t; i < NS; i += 256) {
    int gi = b * NS + i;
    int lab = (i64 ? lr[2 * gi] : lr[gi]) & 15;
    labs[i] = lab;
    atomicAdd(&cnt[lab], 1);
  }
#pragma unroll
  for (int L = 0; L < 16; ++L) hist[t][L] = 0;
  __syncthreads();
  // Own labels (4 contiguous anchors per thread) + own histogram row.
  int lab4[4];
#pragma unroll
  for (int e = 0; e < 4; ++e) {
    lab4[e] = labs[t * 4 + e];
    hist[t][lab4[e]]++;
  }
  __syncthreads();
  // Inclusive Hillis-Steele scan over the 256 rows, 16 bins wide.
#pragma unroll
  for (int off = 1; off < 256; off <<= 1) {
    int tmp[16];
#pragma unroll
    for (int L = 0; L < 16; ++L) tmp[L] = (t >= off) ? hist[t - off][L] : 0;
    __syncthreads();
#pragma unroll
    for (int L = 0; L < 16; ++L) hist[t][L] += tmp[L];
    __syncthreads();
  }
  // Exclusive prefix of group counts -> group start offsets.
  if (t == 0) {
    int s = 0;
#pragma unroll
    for (int L = 0; L < 16; ++L) {
      startL[L] = s;
      s += cnt[L];
    }
  }
  __syncthreads();
  // Emit packed order: row index (10 bits) | nlat << 12.
#pragma unroll
  for (int e = 0; e < 4; ++e) {
    int i = t * 4 + e;
    int lab = lab4[e];
    int later_own = 0;
#pragma unroll
    for (int e2 = 0; e2 < 4; ++e2)
      if (e2 > e && lab4[e2] == lab) later_own++;
    int rank = hist[t][lab] - 1 - later_own;
    int nlat = cnt[lab] - 1 - rank;
    orderP[b * NS + startL[lab] + rank] = i | (nlat << 12);
  }
  if (t < 16) {
    startG[b * 16 + t] = startL[t];
    cntI[b * 16 + t] = cnt[t];
  }
  if (b == 0 && t == 0) out[0] = 0.0f;
}

// ---------------- Kernel 2: one-pass group accumulators --------------------
// Grid 512 = 32 batches x 16 labels, 192 threads (3 waves); thread t owns
// dims 4t..4t+3. Streams the group's gathered rows (3 KB contiguous each)
// with 16 loads in flight; per row: g += v, h += nlat*v, ssq += v.v.
// Row index/weight are wave-uniform (readfirstlane). No atomics, no label
// logic, single-writer stores.
__global__ __launch_bounds__(192) void gsum_kernel(
    const float* __restrict__ feat, const int* __restrict__ orderP,
    const int* __restrict__ startG, const int* __restrict__ cntI,
    float* __restrict__ g, float* __restrict__ h, float* __restrict__ ssq) {
  const int b = blockIdx.x >> 4, lab = blockIdx.x & 15;
  const int start = startG[b * 16 + lab];
  const int n = cntI[b * 16 + lab];
  const int t = threadIdx.x;
  __shared__ int ord[NS];  // 4 KB; handles any group size
  for (int i = t; i < n; i += 192) ord[i] = orderP[b * NS + start + i];
  __syncthreads();
  const float* fb = feat + (size_t)b * NS * ND;
  float gx = 0.f, gy = 0.f, gz = 0.f, gw = 0.f;
  float hx = 0.f, hy = 0.f, hz = 0.f, hw = 0.f;
  float sq = 0.f;
  const int full = n & ~15;
  for (int r = 0; r < full; r += 16) {
    float4 v[16];
    float wt[16];
#pragma unroll
    for (int u = 0; u < 16; ++u) {
      const int p = __builtin_amdgcn_readfirstlane(ord[r + u]);
      wt[u] = (float)(p >> 12);
      v[u] = *(const float4*)(fb + (size_t)(p & 1023) * ND + 4 * t);
    }
#pragma unroll
    for (int u = 0; u < 16; ++u) {
      gx += v[u].x; gy += v[u].y; gz += v[u].z; gw += v[u].w;
      hx += wt[u] * v[u].x; hy += wt[u] * v[u].y;
      hz += wt[u] * v[u].z; hw += wt[u] * v[u].w;
      sq += v[u].x * v[u].x + v[u].y * v[u].y + v[u].z * v[u].z +
            v[u].w * v[u].w;
    }
  }
  if (full < n) {  // masked tail batch: loads stay pipelined, adds masked
    const int rem = n - full;  // 1..15
    float4 v[16];
    float wt[16], msk[16];
#pragma unroll
    for (int u = 0; u < 16; ++u) {
      int rr = full + (u < rem ? u : rem - 1);
      const int p = __builtin_amdgcn_readfirstlane(ord[rr]);
      wt[u] = (float)(p >> 12);
      msk[u] = (u < rem) ? 1.0f : 0.0f;
      v[u] = *(const float4*)(fb + (size_t)(p & 1023) * ND + 4 * t);
    }
#pragma unroll
    for (int u = 0; u < 16; ++u) {
      const float m = msk[u];
      gx += m * v[u].x; gy += m * v[u].y; gz += m * v[u].z; gw += m * v[u].w;
      const float mw = m * wt[u];
      hx += mw * v[u].x; hy += mw * v[u].y;
      hz += mw * v[u].z; hw += mw * v[u].w;
      sq += m * (v[u].x * v[u].x + v[u].y * v[u].y + v[u].z * v[u].z +
                 v[u].w * v[u].w);
    }
  }
  const size_t base = (size_t)(b * 16 + lab) * ND + 4 * t;
  *(float4*)(g + base) = make_float4(gx, gy, gz, gw);
  *(float4*)(h + base) = make_float4(hx, hy, hz, hw);
  // Reduce ssq across the block (3 waves).
#pragma unroll
  for (int m = 1; m < 64; m <<= 1) sq += __shfl_xor(sq, m);
  __shared__ float red[3];
  if ((t & 63) == 0) red[t >> 6] = sq;
  __syncthreads();
  if (t == 0) ssq[b * 16 + lab] = red[0] + red[1] + red[2];
}

// ---------------- Kernel 3: combine group stats -> loss --------------------
// 32 blocks x 192 threads; g/h are 3 MB total, just written -> L2-resident.
__global__ __launch_bounds__(192) void final_kernel(
    const float* __restrict__ g, const float* __restrict__ h,
    const float* __restrict__ ssq, const int* __restrict__ cntI,
    float* __restrict__ out) {
  const int b = blockIdx.x, t = threadIdx.x;
  const int w = t >> 6, l = t & 63;
  const float* gb = g + (size_t)b * 16 * ND;
  const float* hb = h + (size_t)b * 16 * ND;
  float4 gv[16], hv[16];
#pragma unroll
  for (int P = 0; P < 16; ++P) {
    gv[P] = *(const float4*)(gb + P * ND + 4 * t);
    hv[P] = *(const float4*)(hb + P * ND + 4 * t);
  }
  float4 G4 = make_float4(0.f, 0.f, 0.f, 0.f);
#pragma unroll
  for (int P = 0; P < 16; ++P) {
    G4.x += gv[P].x; G4.y += gv[P].y; G4.z += gv[P].z; G4.w += gv[P].w;
  }
  float hd[16], gg[16];
#pragma unroll
  for (int P = 0; P < 16; ++P) {
    hd[P] = hv[P].x * (G4.x - gv[P].x) + hv[P].y * (G4.y - gv[P].y) +
            hv[P].z * (G4.z - gv[P].z) + hv[P].w * (G4.w - gv[P].w);
    gg[P] = gv[P].x * gv[P].x + gv[P].y * gv[P].y + gv[P].z * gv[P].z +
            gv[P].w * gv[P].w;
  }
#pragma unroll
  for (int m = 1; m < 64; m <<= 1)
#pragma unroll
    for (int P = 0; P < 16; ++P) {
      hd[P] += __shfl_xor(hd[P], m);
      gg[P] += __shfl_xor(gg[P], m);
    }
  __shared__ float rh[3][16], rg[3][16];
  if (l == 0)
#pragma unroll
    for (int P = 0; P < 16; ++P) {
      rh[w][P] = hd[P];
      rg[w][P] = gg[P];
    }
  __syncthreads();
  if (t < 16) {
    float shd = rh[0][t] + rh[1][t] + rh[2][t];
    float sgg = rg[0][t] + rg[1][t] + rg[2][t];
    float c = (float)cntI[b * 16 + t];
    float nn = (float)NS - c;
    float val = 0.0f;
    if (c > 0.5f && nn > 0.5f) {
      float invGS = 1.0f / c;
      float sumNlat = 0.5f * c * (c - 1.0f);
      val = invGS * (sumNlat * logf(nn) + (SCALE / (nn * nn)) * shd +
                     0.5f * SCALE * (ssq[b * 16 + t] - sgg));
    }
#pragma unroll
    for (int m = 1; m < 16; m <<= 1) val += __shfl_xor(val, m);
    if (t == 0) atomicAdd(out, val * (1.0f / NS));
  }
}

extern "C" void kernel_launch(void* const* d_in, const int* in_sizes, int n_in,
                              void* d_out, int out_size, void* d_ws,
                              size_t ws_size, hipStream_t stream) {
  (void)out_size;
  (void)ws_size;
  const float* feat = (const float*)d_in[0];
  const int* labels = (const int*)d_in[1];
  float* out = (float*)d_out;
  // Labels dtype resolved host-side from the input byte size.
  const int i64 = (n_in > 1 && in_sizes[1] == BS_TOT * 4) ? 0 : 1;

  char* w = (char*)d_ws;
  int* orderP = (int*)w;  // [32][1024] packed row|nlat<<12
  size_t off = (size_t)BS_TOT * 4;
  int* startG = (int*)(w + off);  // [32][16]
  off += (size_t)NB * 16 * 4;
  int* cntI = (int*)(w + off);  // [32][16]
  off += (size_t)NB * 16 * 4;
  float* g = (float*)(w + off);  // [32][16][768] = 1.5 MB
  off += (size_t)NB * 16 * ND * 4;
  float* h = (float*)(w + off);  // [32][16][768] = 1.5 MB
  off += (size_t)NB * 16 * ND * 4;
  float* ssq = (float*)(w + off);  // [32][16]
  off += (size_t)NB * 16 * 4;
  // total ws usage ~3.3 MB

  meta_kernel<<<NB, 256, 0, stream>>>(labels, i64, orderP, startG, cntI, out);
  gsum_kernel<<<NB * 16, 192, 0, stream>>>(feat, orderP, startG, cntI, g, h,
                                           ssq);
  final_kernel<<<NB, 192, 0, stream>>>(g, h, ssq, cntI, out);
}